// Round 16
// baseline (540.551 us; speedup 1.0000x reference)
//
#include <hip/hip_runtime.h>
#include <hip/hip_bf16.h>

#define H_DIM 2048
#define E_NUM 8
#define I_DIM 4096
#define TWO_I 8192
#define T_TOK 2048

#define BM 128
#define BN 64
#define BK 64

typedef __bf16 bf16x8 __attribute__((ext_vector_type(8)));
typedef float f32x4 __attribute__((ext_vector_type(4)));

static __device__ __forceinline__ unsigned short f2bs(float x) {
    __hip_bfloat16 h = __float2bfloat16(x);
    return __builtin_bit_cast(unsigned short, h);
}

#define GLL(gsrc, ldst) __builtin_amdgcn_global_load_lds( \
    (const __attribute__((address_space(1))) void*)(gsrc), \
    (__attribute__((address_space(3))) void*)(ldst), 16, 0, 0)

#define MFMA16(a, b, c) __builtin_amdgcn_mfma_f32_16x16x32_bf16(a, b, c, 0, 0, 0)
#define BSWZ(n) (((((n) & 7) ^ (((n) >> 2) & 7))) << 4)
#define A_SRC_CHUNK(lane) ((((lane) & 7) ^ (((lane) >> 3) & 7)) * 8)
// barrier WITHOUT vmcnt drain: LDS writes visible; global/GLL loads stay in flight
#define BARRIER() asm volatile("s_waitcnt lgkmcnt(0)\ns_barrier" ::: "memory")

static __device__ __forceinline__ bf16x8 bload(
    const unsigned short* __restrict__ Bs, int n, int s, int h) {
    int off = (n * 128 + s * 64 + h * 16) ^ BSWZ(n);
    return *reinterpret_cast<const bf16x8*>((const char*)Bs + off);
}

static __device__ __forceinline__ bf16x8 aload(
    const unsigned short* __restrict__ As, int row, int s, int h) {
    int off = row * 128 + ((s * 64 + h * 16) ^ ((row & 7) << 4));
    return *reinterpret_cast<const bf16x8*>((const char*)As + off);
}

// ---------------- fused router + convert: one wave per token ----------------
// Outputs: out_scores (dense [E][T]), eidx, score[tok], xb = bf16(x).
// (xs removed: score is applied in gemm1's epilogue by linearity.)
__global__ __launch_bounds__(256) void router_convert_kernel(
    const float* __restrict__ hs, const float* __restrict__ rw,
    float* __restrict__ out_scores, int* __restrict__ eidx,
    float* __restrict__ score, unsigned short* __restrict__ xb) {
    int tok = blockIdx.x * 4 + (threadIdx.x >> 6);
    int lane = threadIdx.x & 63;
    const float* row = hs + (size_t)tok * H_DIM;
    float4 v[8];
    float acc[E_NUM];
#pragma unroll
    for (int e = 0; e < E_NUM; e++) acc[e] = 0.f;
#pragma unroll
    for (int i = 0; i < 8; i++) {
        int hb = i * 256 + lane * 4;
        v[i] = *reinterpret_cast<const float4*>(row + hb);
        const float* w0 = rw + (size_t)hb * E_NUM;
#pragma unroll
        for (int e = 0; e < E_NUM; e++) {
            acc[e] += v[i].x * w0[e] + v[i].y * w0[E_NUM + e] +
                      v[i].z * w0[2 * E_NUM + e] + v[i].w * w0[3 * E_NUM + e];
        }
    }
#pragma unroll
    for (int e = 0; e < E_NUM; e++) {
#pragma unroll
        for (int o = 32; o > 0; o >>= 1) acc[e] += __shfl_xor(acc[e], o, 64);
    }
    int best = 0; float bv = acc[0];
#pragma unroll
    for (int e = 1; e < E_NUM; e++) { if (acc[e] > bv) { bv = acc[e]; best = e; } }
    float sc = 1.f / (1.f + expf(-bv));
    if (lane < E_NUM) out_scores[(size_t)lane * T_TOK + tok] = (lane == best) ? sc : 0.f;
    if (lane == 0) { eidx[tok] = best; score[tok] = sc; }
    unsigned short* xbr = xb + (size_t)tok * H_DIM;
#pragma unroll
    for (int i = 0; i < 8; i++) {
        int hb = i * 256 + lane * 4;
        ushort4 b;
        b.x = f2bs(v[i].x); b.y = f2bs(v[i].y); b.z = f2bs(v[i].z); b.w = f2bs(v[i].w);
        *reinterpret_cast<ushort4*>(xbr + hb) = b;
    }
}

// ---------------- grouping ----------------
__global__ void group_kernel(const int* __restrict__ eidx, int* __restrict__ perm,
                             int* __restrict__ off) {
    __shared__ int cnt[E_NUM];
    __shared__ int base[E_NUM];
    int t = threadIdx.x;
    if (t < E_NUM) cnt[t] = 0;
    __syncthreads();
    for (int i = t; i < T_TOK; i += 256) atomicAdd(&cnt[eidx[i]], 1);
    __syncthreads();
    if (t == 0) {
        int s = 0;
        for (int e = 0; e < E_NUM; e++) { base[e] = s; off[e] = s; s += cnt[e]; }
        off[E_NUM] = s;
    }
    __syncthreads();
    for (int i = t; i < T_TOK; i += 256) {
        int e = eidx[i];
        int p = atomicAdd(&base[e], 1);
        perm[p] = i;
    }
}

// ---------------- GEMM1: R15 schedule, BM=128, 48 KB LDS -> 3 blocks/CU (24 waves)
// 512 thr = 8 waves x 16 rows. BN=64 gate + 64 up, BK=64. As dbuf (GLL), B reg-staged.
// grid.x = I/64, grid.y = g*16 + mt
__global__ __launch_bounds__(512, 6) void gemm1_kernel(
    const unsigned short* __restrict__ xb, const float* __restrict__ gup,
    const float* __restrict__ sg, const float* __restrict__ su,
    const int* __restrict__ perm, const int* __restrict__ off,
    const float* __restrict__ score, unsigned short* __restrict__ hmid) {
    int nt = blockIdx.x;
    int g = blockIdx.y >> 4;
    int mt = blockIdx.y & 15;
    int rowbase, ng;
    if (g < E_NUM) { rowbase = off[g]; ng = off[g + 1] - rowbase; }
    else { rowbase = 0; ng = T_TOK; }
    int mstart = mt * BM;
    if (mstart >= ng) return;

    __shared__ unsigned short As[2][BM * BK];  // 2 x 16 KB
    __shared__ unsigned short Bg[BN * BK];     // 8 KB
    __shared__ unsigned short Bu[BN * BK];     // 8 KB

    int tid = threadIdx.x;
    int wave = tid >> 6, lane = tid & 63;
    int h = lane >> 4, ln = lane & 15;

    unsigned int aoff[2];
#pragma unroll
    for (int j = 0; j < 2; j++) {
        int r = wave * 16 + j * 8 + (lane >> 3);
        int sr = mstart + r; sr = (sr < ng) ? sr : (ng - 1);
        int tokr = (g < E_NUM) ? perm[rowbase + sr] : sr;
        aoff[j] = (unsigned int)tokr * H_DIM + A_SRC_CHUNK(lane);
    }
    int n0 = nt * BN;
    const float* gbase;
    const float* ubase;
    size_t ldb;
    if (g < E_NUM) {
        gbase = gup + (size_t)g * H_DIM * TWO_I + n0;
        ubase = gbase + I_DIM;
        ldb = TWO_I;
    } else {
        gbase = sg + n0;
        ubase = su + n0;
        ldb = I_DIM;
    }
    int k0i = (tid >> 4) * 2;       // 2 k-rows per thread (32 groups cover 64)
    int nb = (tid & 15) * 4;        // 4 n-cols per thread (16 groups cover 64)
    const float* pg = gbase + (size_t)k0i * ldb + nb;
    const float* pu = ubase + (size_t)k0i * ldb + nb;

    f32x4 zero = {0.f, 0.f, 0.f, 0.f};
    f32x4 accg[4], accu[4];
#pragma unroll
    for (int j = 0; j < 4; j++) { accg[j] = zero; accu[j] = zero; }

    const int NT = H_DIM / BK;   // 32
    f32x4 qg0, qg1, qu0, qu1;

#define G1_QLOAD(t_) { size_t ko_ = (size_t)(t_) * BK * ldb; \
        qg0 = *reinterpret_cast<const f32x4*>(pg + ko_); \
        qg1 = *reinterpret_cast<const f32x4*>(pg + ko_ + ldb); \
        qu0 = *reinterpret_cast<const f32x4*>(pu + ko_); \
        qu1 = *reinterpret_cast<const f32x4*>(pu + ko_ + ldb); }
#define G1_BWRITE() { _Pragma("unroll") \
        for (int i_ = 0; i_ < 4; i_++) { int n_ = nb + i_; \
            unsigned og_ = (unsigned)f2bs(qg0[i_]) | ((unsigned)f2bs(qg1[i_]) << 16); \
            unsigned ou_ = (unsigned)f2bs(qu0[i_]) | ((unsigned)f2bs(qu1[i_]) << 16); \
            int ob_ = (n_ * 128 + k0i * 2) ^ BSWZ(n_); \
            *reinterpret_cast<unsigned*>((char*)Bg + ob_) = og_; \
            *reinterpret_cast<unsigned*>((char*)Bu + ob_) = ou_; } }
#define G1_AGLL(t_, buf_) { _Pragma("unroll") \
        for (int j_ = 0; j_ < 2; j_++) \
            GLL(xb + aoff[j_] + (unsigned)(t_) * BK, \
                &As[buf_][(wave * 16 + j_ * 8) * BK]); }

    // prologue: B(0)->LDS, A(0)->As[0], A(1)->As[1], B(1)->regs
    G1_QLOAD(0);
    G1_AGLL(0, 0);
    asm volatile("s_waitcnt vmcnt(0)" ::: "memory");
    G1_BWRITE();
    G1_AGLL(1, 1);
    G1_QLOAD(1);
    BARRIER();

    for (int t = 0; t < NT; ++t) {
        const unsigned short* Ab = &As[t & 1][0];
#pragma unroll
        for (int s = 0; s < 2; s++) {
            bf16x8 a0 = aload(Ab, wave * 16 + ln, s, h);
#pragma unroll
            for (int j = 0; j < 4; j++) {
                bf16x8 bg = bload(Bg, j * 16 + ln, s, h);
                accg[j] = MFMA16(a0, bg, accg[j]);
            }
#pragma unroll
            for (int j = 0; j < 4; j++) {
                bf16x8 bu = bload(Bu, j * 16 + ln, s, h);
                accu[j] = MFMA16(a0, bu, accu[j]);
            }
        }
        BARRIER();                       // reads of As[t&1], B(t) done
        if (t + 1 < NT) {
            G1_BWRITE();                 // B(t+1); implicit vmcnt drain (R9 semantics)
            int tc = t + 2; if (tc > NT - 1) tc = NT - 1;
            G1_AGLL(tc, t & 1);          // A(t+2) into the buffer just read
            G1_QLOAD(tc);                // B(t+2) -> regs, stays in flight
            BARRIER();                   // B(t+1) visible; loads NOT drained
        }
    }

    int hbase = (g < E_NUM) ? rowbase : T_TOK;
#pragma unroll
    for (int r = 0; r < 4; r++) {
        int row = wave * 16 + h * 4 + r;
        int sr = mstart + row;
        if (sr < ng) {
            float sc = 1.f;
            if (g < E_NUM) sc = score[perm[rowbase + sr]];
#pragma unroll
            for (int j = 0; j < 4; j++) {
                float gv = accg[j][r] * sc, uv = accu[j][r] * sc;
                float hv = gv / (1.f + expf(-gv)) * uv;  // silu(s*g)*(s*u)
                int col = n0 + j * 16 + ln;
                hmid[(size_t)(hbase + sr) * I_DIM + col] = f2bs(hv);
            }
        }
    }
}

// ---------------- GEMM2: R15 schedule, BM=128, 40 KB LDS -> 4 blocks/CU ----------
// 512 thr = 8 waves x 16 rows. BN=64, BK=64. ADD=0 shared writes, ADD=1 routed +=
// grid.x = H/64. ADD=0: grid.y=mt(0..15); ADD=1: g*16+mt
template <int ADD>
__global__ __launch_bounds__(512, 6) void gemm2_kernel(
    const unsigned short* __restrict__ hmid, const float* __restrict__ dwn,
    const float* __restrict__ sd, const int* __restrict__ perm,
    const int* __restrict__ off, float* __restrict__ out) {
    int nt = blockIdx.x;
    int g, mt, rowbase, ng, hbase;
    if (ADD) {
        g = blockIdx.y >> 4; mt = blockIdx.y & 15;
        rowbase = off[g]; ng = off[g + 1] - rowbase; hbase = rowbase;
    } else {
        g = E_NUM; mt = blockIdx.y; rowbase = 0; ng = T_TOK; hbase = T_TOK;
    }
    int mstart = mt * BM;
    if (mstart >= ng) return;

    __shared__ unsigned short As[2][BM * BK];  // 2 x 16 KB
    __shared__ unsigned short Bs[BN * BK];     // 8 KB

    int tid = threadIdx.x;
    int wave = tid >> 6, lane = tid & 63;
    int h = lane >> 4, ln = lane & 15;

    unsigned int aoff[2];
#pragma unroll
    for (int j = 0; j < 2; j++) {
        int r = wave * 16 + j * 8 + (lane >> 3);
        int sr = mstart + r; sr = (sr < ng) ? sr : (ng - 1);
        aoff[j] = (unsigned int)(hbase + sr) * I_DIM + A_SRC_CHUNK(lane);
    }
    int n0 = nt * BN;
    const float* bbase = ADD ? (dwn + (size_t)g * I_DIM * H_DIM + n0) : (sd + n0);
    const size_t ldb = H_DIM;
    int k0i = (tid >> 4) * 2;
    int nb = (tid & 15) * 4;
    const float* pb = bbase + (size_t)k0i * ldb + nb;

    f32x4 zero = {0.f, 0.f, 0.f, 0.f};
    f32x4 acc[4];
#pragma unroll
    for (int j = 0; j < 4; j++) acc[j] = zero;

    const int NT2 = I_DIM / BK;  // 64
    f32x4 qb0, qb1;

#define G2_QLOAD(t_) { size_t ko_ = (size_t)(t_) * BK * ldb; \
        qb0 = *reinterpret_cast<const f32x4*>(pb + ko_); \
        qb1 = *reinterpret_cast<const f32x4*>(pb + ko_ + ldb); }
#define G2_BWRITE() { _Pragma("unroll") \
        for (int i_ = 0; i_ < 4; i_++) { int n_ = nb + i_; \
            unsigned o_ = (unsigned)f2bs(qb0[i_]) | ((unsigned)f2bs(qb1[i_]) << 16); \
            int ob_ = (n_ * 128 + k0i * 2) ^ BSWZ(n_); \
            *reinterpret_cast<unsigned*>((char*)Bs + ob_) = o_; } }
#define G2_AGLL(t_, buf_) { _Pragma("unroll") \
        for (int j_ = 0; j_ < 2; j_++) \
            GLL(hmid + aoff[j_] + (unsigned)(t_) * BK, \
                &As[buf_][(wave * 16 + j_ * 8) * BK]); }

    G2_QLOAD(0);
    G2_AGLL(0, 0);
    asm volatile("s_waitcnt vmcnt(0)" ::: "memory");
    G2_BWRITE();
    G2_AGLL(1, 1);
    G2_QLOAD(1);
    BARRIER();

    for (int t = 0; t < NT2; ++t) {
        const unsigned short* Ab = &As[t & 1][0];
#pragma unroll
        for (int s = 0; s < 2; s++) {
            bf16x8 a0 = aload(Ab, wave * 16 + ln, s, h);
#pragma unroll
            for (int j = 0; j < 4; j++) {
                bf16x8 b = bload(Bs, j * 16 + ln, s, h);
                acc[j] = MFMA16(a0, b, acc[j]);
            }
        }
        BARRIER();
        if (t + 1 < NT2) {
            G2_BWRITE();
            int tc = t + 2; if (tc > NT2 - 1) tc = NT2 - 1;
            G2_AGLL(tc, t & 1);
            G2_QLOAD(tc);
            BARRIER();
        }
    }

#pragma unroll
    for (int r = 0; r < 4; r++) {
        int row = wave * 16 + h * 4 + r;
        int sr = mstart + row;
        if (sr < ng) {
            int tok = ADD ? perm[rowbase + sr] : sr;
#pragma unroll
            for (int j = 0; j < 4; j++) {
                int col = n0 + j * 16 + ln;
                float v = acc[j][r];
                float* o = out + (size_t)tok * H_DIM + col;
                if (ADD) *o += v; else *o = v;
            }
        }
    }
}

extern "C" void kernel_launch(void* const* d_in, const int* in_sizes, int n_in,
                              void* d_out, int out_size, void* d_ws, size_t ws_size,
                              hipStream_t stream) {
    (void)in_sizes; (void)n_in; (void)out_size;
    const float* hs  = (const float*)d_in[0];
    const float* rw  = (const float*)d_in[1];
    const float* gup = (const float*)d_in[2];
    const float* dwn = (const float*)d_in[3];
    const float* sg  = (const float*)d_in[4];
    const float* su  = (const float*)d_in[5];
    const float* sd  = (const float*)d_in[6];
    float* out = (float*)d_out;
    float* out_scores = out + (size_t)T_TOK * H_DIM;

    char* w = (char*)d_ws;
    size_t o = 0;
    auto alloc = [&](size_t bytes) {
        void* p = w + o;
        o += (bytes + 255) & ~(size_t)255;
        return p;
    };
    unsigned short* xb   = (unsigned short*)alloc((size_t)T_TOK * H_DIM * 2);
    unsigned short* hmid = (unsigned short*)alloc((size_t)2 * T_TOK * I_DIM * 2);
    float* score = (float*)alloc(T_TOK * 4);
    int* eidx    = (int*)alloc(T_TOK * 4);
    int* perm    = (int*)alloc(T_TOK * 4);
    int* off     = (int*)alloc(64 * 4);
    if (ws_size < o) return;  // insufficient workspace

    router_convert_kernel<<<T_TOK / 4, 256, 0, stream>>>(hs, rw, out_scores, eidx, score, xb);
    group_kernel<<<1, 256, 0, stream>>>(eidx, perm, off);

    gemm1_kernel<<<dim3(I_DIM / BN, 9 * 16), 512, 0, stream>>>(
        xb, gup, sg, su, perm, off, score, hmid);
    gemm2_kernel<0><<<dim3(H_DIM / BN, 16), 512, 0, stream>>>(hmid, dwn, sd, perm, off, out);
    gemm2_kernel<1><<<dim3(H_DIM / BN, E_NUM * 16), 512, 0, stream>>>(hmid, dwn, sd, perm, off, out);
}

// Round 17
// 473.284 us; speedup vs baseline: 1.1421x; 1.1421x over previous
//
#include <hip/hip_runtime.h>
#include <hip/hip_bf16.h>

#define H_DIM 2048
#define E_NUM 8
#define I_DIM 4096
#define TWO_I 8192
#define T_TOK 2048

#define BM 256
#define BN 64
#define BK 64

typedef __bf16 bf16x8 __attribute__((ext_vector_type(8)));
typedef float f32x4 __attribute__((ext_vector_type(4)));

static __device__ __forceinline__ unsigned short f2bs(float x) {
    __hip_bfloat16 h = __float2bfloat16(x);
    return __builtin_bit_cast(unsigned short, h);
}

#define GLL(gsrc, ldst) __builtin_amdgcn_global_load_lds( \
    (const __attribute__((address_space(1))) void*)(gsrc), \
    (__attribute__((address_space(3))) void*)(ldst), 16, 0, 0)

#define MFMA16(a, b, c) __builtin_amdgcn_mfma_f32_16x16x32_bf16(a, b, c, 0, 0, 0)
#define BSWZ(n) (((((n) & 7) ^ (((n) >> 2) & 7))) << 4)
#define A_SRC_CHUNK(lane) ((((lane) & 7) ^ (((lane) >> 3) & 7)) * 8)
// barrier WITHOUT vmcnt drain: LDS writes visible; global/GLL loads stay in flight
#define BARRIER() asm volatile("s_waitcnt lgkmcnt(0)\ns_barrier" ::: "memory")

static __device__ __forceinline__ bf16x8 bload(
    const unsigned short* __restrict__ Bs, int n, int s, int h) {
    int off = (n * 128 + s * 64 + h * 16) ^ BSWZ(n);
    return *reinterpret_cast<const bf16x8*>((const char*)Bs + off);
}

static __device__ __forceinline__ bf16x8 aload(
    const unsigned short* __restrict__ As, int row, int s, int h) {
    int off = row * 128 + ((s * 64 + h * 16) ^ ((row & 7) << 4));
    return *reinterpret_cast<const bf16x8*>((const char*)As + off);
}

// ---------------- fused router + convert: one wave per token ----------------
// Outputs: out_scores (dense [E][T]), eidx, score[tok], xb = bf16(x).
// (xs eliminated: score applied in gemm1's f32 epilogue by linearity.)
__global__ __launch_bounds__(256) void router_convert_kernel(
    const float* __restrict__ hs, const float* __restrict__ rw,
    float* __restrict__ out_scores, int* __restrict__ eidx,
    float* __restrict__ score, unsigned short* __restrict__ xb) {
    int tok = blockIdx.x * 4 + (threadIdx.x >> 6);
    int lane = threadIdx.x & 63;
    const float* row = hs + (size_t)tok * H_DIM;
    float4 v[8];
    float acc[E_NUM];
#pragma unroll
    for (int e = 0; e < E_NUM; e++) acc[e] = 0.f;
#pragma unroll
    for (int i = 0; i < 8; i++) {
        int hb = i * 256 + lane * 4;
        v[i] = *reinterpret_cast<const float4*>(row + hb);
        const float* w0 = rw + (size_t)hb * E_NUM;
#pragma unroll
        for (int e = 0; e < E_NUM; e++) {
            acc[e] += v[i].x * w0[e] + v[i].y * w0[E_NUM + e] +
                      v[i].z * w0[2 * E_NUM + e] + v[i].w * w0[3 * E_NUM + e];
        }
    }
#pragma unroll
    for (int e = 0; e < E_NUM; e++) {
#pragma unroll
        for (int o = 32; o > 0; o >>= 1) acc[e] += __shfl_xor(acc[e], o, 64);
    }
    int best = 0; float bv = acc[0];
#pragma unroll
    for (int e = 1; e < E_NUM; e++) { if (acc[e] > bv) { bv = acc[e]; best = e; } }
    float sc = 1.f / (1.f + expf(-bv));
    if (lane < E_NUM) out_scores[(size_t)lane * T_TOK + tok] = (lane == best) ? sc : 0.f;
    if (lane == 0) { eidx[tok] = best; score[tok] = sc; }
    unsigned short* xbr = xb + (size_t)tok * H_DIM;
#pragma unroll
    for (int i = 0; i < 8; i++) {
        int hb = i * 256 + lane * 4;
        ushort4 b;
        b.x = f2bs(v[i].x); b.y = f2bs(v[i].y); b.z = f2bs(v[i].z); b.w = f2bs(v[i].w);
        *reinterpret_cast<ushort4*>(xbr + hb) = b;
    }
}

// ---------------- grouping ----------------
__global__ void group_kernel(const int* __restrict__ eidx, int* __restrict__ perm,
                             int* __restrict__ off) {
    __shared__ int cnt[E_NUM];
    __shared__ int base[E_NUM];
    int t = threadIdx.x;
    if (t < E_NUM) cnt[t] = 0;
    __syncthreads();
    for (int i = t; i < T_TOK; i += 256) atomicAdd(&cnt[eidx[i]], 1);
    __syncthreads();
    if (t == 0) {
        int s = 0;
        for (int e = 0; e < E_NUM; e++) { base[e] = s; off[e] = s; s += cnt[e]; }
        off[E_NUM] = s;
    }
    __syncthreads();
    for (int i = t; i < T_TOK; i += 256) {
        int e = eidx[i];
        int p = atomicAdd(&base[e], 1);
        perm[p] = i;
    }
}

// ---------------- GEMM1: R15 schedule, 512 thr (8 waves x 32 rows), score in epilogue
// BM=256, BN=64 gate + 64 up, BK=64. As dbuf (GLL), B single-buf reg-staged. 80 KB LDS.
// grid.x = I/64, grid.y = g*8 + mt
__global__ __launch_bounds__(512, 4) void gemm1_kernel(
    const unsigned short* __restrict__ xb, const float* __restrict__ gup,
    const float* __restrict__ sg, const float* __restrict__ su,
    const int* __restrict__ perm, const int* __restrict__ off,
    const float* __restrict__ score, unsigned short* __restrict__ hmid) {
    int nt = blockIdx.x;
    int g = blockIdx.y >> 3;
    int mt = blockIdx.y & 7;
    int rowbase, ng;
    if (g < E_NUM) { rowbase = off[g]; ng = off[g + 1] - rowbase; }
    else { rowbase = 0; ng = T_TOK; }
    int mstart = mt * BM;
    if (mstart >= ng) return;

    __shared__ unsigned short As[2][BM * BK];  // 2 x 32 KB
    __shared__ unsigned short Bg[BN * BK];     // 8 KB
    __shared__ unsigned short Bu[BN * BK];     // 8 KB

    int tid = threadIdx.x;
    int wave = tid >> 6, lane = tid & 63;
    int h = lane >> 4, ln = lane & 15;

    unsigned int aoff[4];
#pragma unroll
    for (int j = 0; j < 4; j++) {
        int r = wave * 32 + j * 8 + (lane >> 3);
        int sr = mstart + r; sr = (sr < ng) ? sr : (ng - 1);
        int tokr = (g < E_NUM) ? perm[rowbase + sr] : sr;
        aoff[j] = (unsigned int)tokr * H_DIM + A_SRC_CHUNK(lane);
    }
    int n0 = nt * BN;
    const float* gbase;
    const float* ubase;
    size_t ldb;
    if (g < E_NUM) {
        gbase = gup + (size_t)g * H_DIM * TWO_I + n0;
        ubase = gbase + I_DIM;
        ldb = TWO_I;
    } else {
        gbase = sg + n0;
        ubase = su + n0;
        ldb = I_DIM;
    }
    int k0i = (tid >> 4) * 2;       // 2 k-rows per thread (32 groups cover 64)
    int nb = (tid & 15) * 4;        // 4 n-cols per thread (16 groups cover 64)
    const float* pg = gbase + (size_t)k0i * ldb + nb;
    const float* pu = ubase + (size_t)k0i * ldb + nb;

    f32x4 zero = {0.f, 0.f, 0.f, 0.f};
    f32x4 accg[2][4], accu[2][4];
#pragma unroll
    for (int i = 0; i < 2; i++)
#pragma unroll
        for (int j = 0; j < 4; j++) { accg[i][j] = zero; accu[i][j] = zero; }

    const int NT = H_DIM / BK;   // 32
    f32x4 qg0, qg1, qu0, qu1;

#define G1_QLOAD(t_) { size_t ko_ = (size_t)(t_) * BK * ldb; \
        qg0 = *reinterpret_cast<const f32x4*>(pg + ko_); \
        qg1 = *reinterpret_cast<const f32x4*>(pg + ko_ + ldb); \
        qu0 = *reinterpret_cast<const f32x4*>(pu + ko_); \
        qu1 = *reinterpret_cast<const f32x4*>(pu + ko_ + ldb); }
#define G1_BWRITE() { _Pragma("unroll") \
        for (int i_ = 0; i_ < 4; i_++) { int n_ = nb + i_; \
            unsigned og_ = (unsigned)f2bs(qg0[i_]) | ((unsigned)f2bs(qg1[i_]) << 16); \
            unsigned ou_ = (unsigned)f2bs(qu0[i_]) | ((unsigned)f2bs(qu1[i_]) << 16); \
            int ob_ = (n_ * 128 + k0i * 2) ^ BSWZ(n_); \
            *reinterpret_cast<unsigned*>((char*)Bg + ob_) = og_; \
            *reinterpret_cast<unsigned*>((char*)Bu + ob_) = ou_; } }
#define G1_AGLL(t_, buf_) { _Pragma("unroll") \
        for (int j_ = 0; j_ < 4; j_++) \
            GLL(xb + aoff[j_] + (unsigned)(t_) * BK, \
                &As[buf_][(wave * 32 + j_ * 8) * BK]); }

    // prologue: B(0)->LDS, A(0)->As[0], A(1)->As[1], B(1)->regs
    G1_QLOAD(0);
    G1_AGLL(0, 0);
    asm volatile("s_waitcnt vmcnt(0)" ::: "memory");
    G1_BWRITE();
    G1_AGLL(1, 1);
    G1_QLOAD(1);
    BARRIER();

    for (int t = 0; t < NT; ++t) {
        const unsigned short* Ab = &As[t & 1][0];
#pragma unroll
        for (int s = 0; s < 2; s++) {
            bf16x8 a0 = aload(Ab, wave * 32 + 0 * 16 + ln, s, h);
            bf16x8 a1 = aload(Ab, wave * 32 + 1 * 16 + ln, s, h);
#pragma unroll
            for (int j = 0; j < 4; j++) {
                bf16x8 bg = bload(Bg, j * 16 + ln, s, h);
                accg[0][j] = MFMA16(a0, bg, accg[0][j]);
                accg[1][j] = MFMA16(a1, bg, accg[1][j]);
            }
#pragma unroll
            for (int j = 0; j < 4; j++) {
                bf16x8 bu = bload(Bu, j * 16 + ln, s, h);
                accu[0][j] = MFMA16(a0, bu, accu[0][j]);
                accu[1][j] = MFMA16(a1, bu, accu[1][j]);
            }
        }
        BARRIER();                       // reads of As[t&1], B(t) done
        if (t + 1 < NT) {
            G1_BWRITE();                 // B(t+1); implicit vmcnt drain (R9 semantics)
            int tc = t + 2; if (tc > NT - 1) tc = NT - 1;
            G1_AGLL(tc, t & 1);          // A(t+2) into the buffer just read
            G1_QLOAD(tc);                // B(t+2) -> regs, stays in flight
            BARRIER();                   // B(t+1) visible; loads NOT drained
        }
    }

    int hbase = (g < E_NUM) ? rowbase : T_TOK;
#pragma unroll
    for (int i = 0; i < 2; i++) {
#pragma unroll
        for (int r = 0; r < 4; r++) {
            int row = wave * 32 + i * 16 + h * 4 + r;
            int sr = mstart + row;
            if (sr < ng) {
                float sc = (g < E_NUM) ? score[perm[rowbase + sr]] : 1.f;
#pragma unroll
                for (int j = 0; j < 4; j++) {
                    float gv = accg[i][j][r] * sc, uv = accu[i][j][r] * sc;
                    float hv = gv / (1.f + expf(-gv)) * uv;  // silu(s*g)*(s*u)
                    int col = n0 + j * 16 + ln;
                    hmid[(size_t)(hbase + sr) * I_DIM + col] = f2bs(hv);
                }
            }
        }
    }
}

// ---------------- GEMM2 merged: routed (g<8) and shared (g=8) co-resident; atomicAdd
// R15 schedule, 512 thr, BM=256, BN=64, BK=64, 72 KB LDS. out must be pre-zeroed.
// grid.x = H/64 (32), grid.y = g*8 + mt (72)
__global__ __launch_bounds__(512, 4) void gemm2_kernel(
    const unsigned short* __restrict__ hmid, const float* __restrict__ dwn,
    const float* __restrict__ sd, const int* __restrict__ perm,
    const int* __restrict__ off, float* __restrict__ out) {
    int nt = blockIdx.x;
    int g = blockIdx.y >> 3;
    int mt = blockIdx.y & 7;
    int rowbase, ng, hbase;
    if (g < E_NUM) { rowbase = off[g]; ng = off[g + 1] - rowbase; hbase = rowbase; }
    else { rowbase = 0; ng = T_TOK; hbase = T_TOK; }
    int mstart = mt * BM;
    if (mstart >= ng) return;

    __shared__ unsigned short As[2][BM * BK];  // 2 x 32 KB
    __shared__ unsigned short Bs[BN * BK];     // 8 KB

    int tid = threadIdx.x;
    int wave = tid >> 6, lane = tid & 63;
    int h = lane >> 4, ln = lane & 15;

    unsigned int aoff[4];
#pragma unroll
    for (int j = 0; j < 4; j++) {
        int r = wave * 32 + j * 8 + (lane >> 3);
        int sr = mstart + r; sr = (sr < ng) ? sr : (ng - 1);
        aoff[j] = (unsigned int)(hbase + sr) * I_DIM + A_SRC_CHUNK(lane);
    }
    int n0 = nt * BN;
    const float* bbase = (g < E_NUM) ? (dwn + (size_t)g * I_DIM * H_DIM + n0) : (sd + n0);
    const size_t ldb = H_DIM;
    int k0i = (tid >> 4) * 2;
    int nb = (tid & 15) * 4;
    const float* pb = bbase + (size_t)k0i * ldb + nb;

    f32x4 zero = {0.f, 0.f, 0.f, 0.f};
    f32x4 acc[2][4];
#pragma unroll
    for (int i = 0; i < 2; i++)
#pragma unroll
        for (int j = 0; j < 4; j++) acc[i][j] = zero;

    const int NT2 = I_DIM / BK;  // 64
    f32x4 qb0, qb1;

#define G2_QLOAD(t_) { size_t ko_ = (size_t)(t_) * BK * ldb; \
        qb0 = *reinterpret_cast<const f32x4*>(pb + ko_); \
        qb1 = *reinterpret_cast<const f32x4*>(pb + ko_ + ldb); }
#define G2_BWRITE() { _Pragma("unroll") \
        for (int i_ = 0; i_ < 4; i_++) { int n_ = nb + i_; \
            unsigned o_ = (unsigned)f2bs(qb0[i_]) | ((unsigned)f2bs(qb1[i_]) << 16); \
            int ob_ = (n_ * 128 + k0i * 2) ^ BSWZ(n_); \
            *reinterpret_cast<unsigned*>((char*)Bs + ob_) = o_; } }
#define G2_AGLL(t_, buf_) { _Pragma("unroll") \
        for (int j_ = 0; j_ < 4; j_++) \
            GLL(hmid + aoff[j_] + (unsigned)(t_) * BK, \
                &As[buf_][(wave * 32 + j_ * 8) * BK]); }

    G2_QLOAD(0);
    G2_AGLL(0, 0);
    asm volatile("s_waitcnt vmcnt(0)" ::: "memory");
    G2_BWRITE();
    G2_AGLL(1, 1);
    G2_QLOAD(1);
    BARRIER();

    for (int t = 0; t < NT2; ++t) {
        const unsigned short* Ab = &As[t & 1][0];
#pragma unroll
        for (int s = 0; s < 2; s++) {
            bf16x8 a0 = aload(Ab, wave * 32 + 0 * 16 + ln, s, h);
            bf16x8 a1 = aload(Ab, wave * 32 + 1 * 16 + ln, s, h);
#pragma unroll
            for (int j = 0; j < 4; j++) {
                bf16x8 b = bload(Bs, j * 16 + ln, s, h);
                acc[0][j] = MFMA16(a0, b, acc[0][j]);
                acc[1][j] = MFMA16(a1, b, acc[1][j]);
            }
        }
        BARRIER();
        if (t + 1 < NT2) {
            G2_BWRITE();
            int tc = t + 2; if (tc > NT2 - 1) tc = NT2 - 1;
            G2_AGLL(tc, t & 1);
            G2_QLOAD(tc);
            BARRIER();
        }
    }

#pragma unroll
    for (int i = 0; i < 2; i++) {
#pragma unroll
        for (int r = 0; r < 4; r++) {
            int row = wave * 32 + i * 16 + h * 4 + r;
            int sr = mstart + row;
            if (sr < ng) {
                int tok = (g < E_NUM) ? perm[rowbase + sr] : sr;
#pragma unroll
                for (int j = 0; j < 4; j++) {
                    int col = n0 + j * 16 + ln;
                    atomicAdd(out + (size_t)tok * H_DIM + col, acc[i][j][r]);
                }
            }
        }
    }
}

extern "C" void kernel_launch(void* const* d_in, const int* in_sizes, int n_in,
                              void* d_out, int out_size, void* d_ws, size_t ws_size,
                              hipStream_t stream) {
    (void)in_sizes; (void)n_in; (void)out_size;
    const float* hs  = (const float*)d_in[0];
    const float* rw  = (const float*)d_in[1];
    const float* gup = (const float*)d_in[2];
    const float* dwn = (const float*)d_in[3];
    const float* sg  = (const float*)d_in[4];
    const float* su  = (const float*)d_in[5];
    const float* sd  = (const float*)d_in[6];
    float* out = (float*)d_out;
    float* out_scores = out + (size_t)T_TOK * H_DIM;

    char* w = (char*)d_ws;
    size_t o = 0;
    auto alloc = [&](size_t bytes) {
        void* p = w + o;
        o += (bytes + 255) & ~(size_t)255;
        return p;
    };
    unsigned short* xb   = (unsigned short*)alloc((size_t)T_TOK * H_DIM * 2);
    unsigned short* hmid = (unsigned short*)alloc((size_t)2 * T_TOK * I_DIM * 2);
    float* score = (float*)alloc(T_TOK * 4);
    int* eidx    = (int*)alloc(T_TOK * 4);
    int* perm    = (int*)alloc(T_TOK * 4);
    int* off     = (int*)alloc(64 * 4);
    if (ws_size < o) return;  // insufficient workspace

    // zero the summed output region (scores region fully overwritten by router)
    hipMemsetAsync(out, 0, (size_t)T_TOK * H_DIM * sizeof(float), stream);

    router_convert_kernel<<<T_TOK / 4, 256, 0, stream>>>(hs, rw, out_scores, eidx, score, xb);
    group_kernel<<<1, 256, 0, stream>>>(eidx, perm, off);

    gemm1_kernel<<<dim3(I_DIM / BN, 9 * 8), 512, 0, stream>>>(
        xb, gup, sg, su, perm, off, score, hmid);
    gemm2_kernel<<<dim3(H_DIM / BN, 9 * 8), 512, 0, stream>>>(
        hmid, dwn, sd, perm, off, out);
}